// Round 1
// baseline (201.226 us; speedup 1.0000x reference)
//
#include <hip/hip_runtime.h>
#include <math.h>

#define IMG_H 4096
#define IMG_W 4096
#define TS 64
#define HALO 3
#define TW (TS + 2*HALO)   // 70

struct SelState {
    unsigned prefix;
    unsigned k_rem;
    float    median;
    unsigned pad;
};

__device__ __forceinline__ unsigned f2u(float f) {
    unsigned b = __float_as_uint(f);
    unsigned mask = (unsigned)(-(int)(b >> 31)) | 0x80000000u;
    return b ^ mask;
}
__device__ __forceinline__ float u2f(unsigned u) {
    unsigned mask = (u >> 31) ? 0x80000000u : 0xFFFFFFFFu;
    return __uint_as_float(u ^ mask);
}

// Histogram pass: count keys matching current prefix into nbins buckets of
// (u >> shift) & (nbins-1). checkshift >= 32 means "no prefix check" (pass 1).
__global__ __launch_bounds__(256) void hist_kernel(
    const float4* __restrict__ x4, int n4, unsigned* __restrict__ gh,
    const SelState* __restrict__ st, int checkshift, int shift, int nbins)
{
    __shared__ unsigned lh[2048];
    for (int i = threadIdx.x; i < nbins; i += blockDim.x) lh[i] = 0;
    unsigned pref = 0;
    const bool docheck = (checkshift < 32);
    if (docheck) pref = st->prefix;
    __syncthreads();

    const unsigned binmask = (unsigned)(nbins - 1);
    int idx = blockIdx.x * blockDim.x + threadIdx.x;
    int stride = gridDim.x * blockDim.x;
    for (int i = idx; i < n4; i += stride) {
        float4 v = x4[i];
        unsigned u;
        u = f2u(v.x); if (!docheck || (u >> checkshift) == pref) atomicAdd(&lh[(u >> shift) & binmask], 1u);
        u = f2u(v.y); if (!docheck || (u >> checkshift) == pref) atomicAdd(&lh[(u >> shift) & binmask], 1u);
        u = f2u(v.z); if (!docheck || (u >> checkshift) == pref) atomicAdd(&lh[(u >> shift) & binmask], 1u);
        u = f2u(v.w); if (!docheck || (u >> checkshift) == pref) atomicAdd(&lh[(u >> shift) & binmask], 1u);
    }
    __syncthreads();
    for (int i = threadIdx.x; i < nbins; i += blockDim.x) {
        unsigned c = lh[i];
        if (c) atomicAdd(&gh[i], c);
    }
}

// Single-block scan: find the bucket containing rank k_rem, update state,
// zero the histogram for the next pass. blockDim.x must be 1024.
__global__ __launch_bounds__(1024) void scan_kernel(
    unsigned* __restrict__ gh, SelState* __restrict__ st,
    int nbins, int bits, unsigned kInit, int useInit, int isFinal)
{
    __shared__ unsigned ps[1024];
    int t = threadIdx.x;
    int P = nbins >> 10;              // 1 or 2 bins per thread
    if (P < 1) P = 1;
    unsigned c0 = 0, c1 = 0;
    c0 = gh[t * P + 0];
    if (P == 2) c1 = gh[t * P + 1];
    unsigned local = c0 + c1;

    unsigned pref = 0, kRem;
    if (useInit) { kRem = kInit; }
    else { kRem = st->k_rem; pref = st->prefix; }

    ps[t] = local;
    __syncthreads();
    // Hillis-Steele inclusive scan over 1024 partials
    for (int off = 1; off < 1024; off <<= 1) {
        unsigned v = ps[t];
        unsigned add = (t >= off) ? ps[t - off] : 0u;
        __syncthreads();
        ps[t] = v + add;
        __syncthreads();
    }
    unsigned incl = ps[t];
    unsigned excl = incl - local;

    if (kRem >= excl && kRem < incl) {
        unsigned cum = excl;
        int b = t * P;
        if (P == 2 && kRem >= cum + c0) { cum += c0; b = t * P + 1; }
        unsigned np = (pref << bits) | (unsigned)b;
        st->prefix = np;
        st->k_rem = kRem - cum;
        if (isFinal) st->median = u2f(np);
    }
    // zero histogram for next pass
    gh[t * P + 0] = 0;
    if (P == 2) gh[t * P + 1] = 0;
}

// Fused: threshold + 7x7 maxpool (pad=-inf) + binarize + multiply by original x.
__global__ __launch_bounds__(256) void nms_kernel(
    const float* __restrict__ x, float* __restrict__ out,
    const SelState* __restrict__ st)
{
    __shared__ float th[TW][TW];   // thresholded values incl. halo, 19.6 KB
    __shared__ float hm[TW][TS];   // horizontal 7-max, 17.9 KB

    const float med = st->median;
    const float NEGINF = -__builtin_inff();

    const int gx0 = blockIdx.x * TS - HALO;
    const int gy0 = blockIdx.y * TS - HALO;

    // load halo tile, apply threshold; OOB = -inf (reference pads with -inf)
    for (int i = threadIdx.x; i < TW * TW; i += 256) {
        int r = i / TW, c = i - r * TW;
        int gy = gy0 + r, gx = gx0 + c;
        float v;
        if (gy >= 0 && gy < IMG_H && gx >= 0 && gx < IMG_W) {
            v = x[gy * IMG_W + gx];
            v = (v < med) ? 0.0f : v;
        } else {
            v = NEGINF;
        }
        th[r][c] = v;
    }
    __syncthreads();

    // horizontal 7-max: hm[r][c] = max(th[r][c..c+6]), c in [0,TS)
    for (int i = threadIdx.x; i < TW * TS; i += 256) {
        int r = i / TS, c = i - r * TS;
        float m = th[r][c];
        #pragma unroll
        for (int k = 1; k < 7; k++) m = fmaxf(m, th[r][c + k]);
        hm[r][c] = m;
    }
    __syncthreads();

    // vertical 7-max + binarize*x
    const int tx = threadIdx.x & 63;
    const int ty = threadIdx.x >> 6;      // 0..3
    for (int rr = ty; rr < TS; rr += 4) {
        float m = hm[rr][tx];
        #pragma unroll
        for (int k = 1; k < 7; k++) m = fmaxf(m, hm[rr + k][tx]);
        float t = th[rr + HALO][tx + HALO];
        int gy = blockIdx.y * TS + rr;
        int gx = blockIdx.x * TS + tx;
        float xv = x[gy * IMG_W + gx];    // L1/L2 hit: tile just loaded
        out[gy * IMG_W + gx] = (t == m) ? xv : 0.0f;
    }
}

extern "C" void kernel_launch(void* const* d_in, const int* in_sizes, int n_in,
                              void* d_out, int out_size, void* d_ws, size_t ws_size,
                              hipStream_t stream)
{
    const float* x = (const float*)d_in[0];
    float* out = (float*)d_out;
    const int n = in_sizes[0];                 // 16777216
    const unsigned K = (unsigned)((n - 1) / 2); // rank of lower-middle element

    unsigned* gh = (unsigned*)d_ws;
    SelState* st = (SelState*)((char*)d_ws + 2048 * sizeof(unsigned));

    // zero histogram + state (ws is re-poisoned 0xAA before every launch)
    hipMemsetAsync(d_ws, 0, 2048 * sizeof(unsigned) + sizeof(SelState), stream);

    const int n4 = n / 4;
    dim3 hb(256), hg(1024);
    // pass 1: bits 31..21 (11 bits)
    hist_kernel<<<hg, hb, 0, stream>>>((const float4*)x, n4, gh, st, 32, 21, 2048);
    scan_kernel<<<1, 1024, 0, stream>>>(gh, st, 2048, 11, K, 1, 0);
    // pass 2: bits 20..10 (11 bits)
    hist_kernel<<<hg, hb, 0, stream>>>((const float4*)x, n4, gh, st, 21, 10, 2048);
    scan_kernel<<<1, 1024, 0, stream>>>(gh, st, 2048, 11, 0, 0, 0);
    // pass 3: bits 9..0 (10 bits)
    hist_kernel<<<hg, hb, 0, stream>>>((const float4*)x, n4, gh, st, 10, 0, 1024);
    scan_kernel<<<1, 1024, 0, stream>>>(gh, st, 1024, 10, 0, 0, 1);

    // fused threshold + 7x7 maxpool + binarize + mul
    dim3 fg(IMG_W / TS, IMG_H / TS), fb(256);
    nms_kernel<<<fg, fb, 0, stream>>>(x, out, st);
}